// Round 8
// baseline (208.194 us; speedup 1.0000x reference)
//
#include <hip/hip_runtime.h>
#include <math.h>

// 10-layer MLP, fp16 MFMA (fp32 acc), grid-stride per wave.
// R8 = R7 + TWO 16-sample tiles in flight per wave: two independent
// layer-chains per wave hide the per-layer LDS write->read round-trip
// (R7: VALUBusy 64% @ 39% occupancy = latency-bound on the serial chain),
// and one weight-frag register read feeds both tiles' MFMAs (halves weight
// ds_read per sample). Frag-packed act layout (R6/R7, validated): B-frag
// read = lane*16B linear, zero read conflicts.
// Bias folded as augmented-K column (marker 1.0 at feature==OUT).

typedef _Float16 half8 __attribute__((ext_vector_type(8)));
typedef _Float16 half4 __attribute__((ext_vector_type(4)));
typedef _Float16 half2 __attribute__((ext_vector_type(2)));
typedef float f32x4 __attribute__((ext_vector_type(4)));

__device__ __forceinline__ float swish_f(float a) {
    float e = __expf(-a);
    return a * __builtin_amdgcn_rcpf(1.0f + e);
}

// One lane's 8 f16 of weight fragment (ot,kt): A-frag layout row=ot*16+lr,
// k=kt*32+kg*8+e. Column k==IN holds the bias (augmented-K); else zero-pad.
__device__ __forceinline__ half8 make_frag(const float* __restrict__ W,
                                           const float* __restrict__ b,
                                           int IN, int OUT, int ot, int kt,
                                           int lr, int kg) {
    const int r = ot * 16 + lr;
    half8 h;
#pragma unroll
    for (int e = 0; e < 8; ++e) {
        const int k = kt * 32 + kg * 8 + e;
        float v = 0.0f;
        if (r < OUT) {
            if (k < IN)
                v = W[r * IN + k];
            else if (k == IN)
                v = b[r];
        }
        h[e] = (_Float16)v;
    }
    return h;
}

// acc[ot][r] = feature ot*16+kg*4+r of sample lr (D^T). Swish all (pad accs
// are 0 -> swish 0), overwrite feature==OUT with 1.0 marker, cvt_pkrtz pack,
// one b64 store into the frag-packed act tile:
//   feature f of sample lr lives at (f>>5)*512 + (((f>>3)&3)*16 + lr)*8 + (f&7)
//   (f16 units); the 4 features of (ot,kg) share one run: kt=ot>>1,
//   lane-group (2ot+(kg>>1))&3, half-select kg&1.
template <int NOT, int OUT>
__device__ __forceinline__ void epilogue(const f32x4 (&acc)[NOT],
                                         _Float16* act, int lr, int kg) {
    const int kgl = kg & 1;
    const int kgh = kg >> 1;
#pragma unroll
    for (int ot = 0; ot < NOT; ++ot) {
        float v[4];
#pragma unroll
        for (int r = 0; r < 4; ++r) {
            v[r] = swish_f(acc[ot][r]);
            if (ot == OUT / 16 && ot * 16 + kg * 4 + r == OUT) v[r] = 1.0f;
        }
        auto lo = __builtin_amdgcn_cvt_pkrtz(v[0], v[1]);
        auto hi = __builtin_amdgcn_cvt_pkrtz(v[2], v[3]);
        union {
            half4 h4;
            half2 h2[2];
        } u;
        u.h2[0] = __builtin_bit_cast(half2, lo);
        u.h2[1] = __builtin_bit_cast(half2, hi);
        _Float16* p = act + (ot >> 1) * 512 +
                      (((2 * ot + kgh) & 3) * 16 + lr) * 8 + kgl * 4;
        *(half4*)p = u.h4;
    }
}

// One layer for BOTH tiles; each weight frag read once, used twice.
template <int NOT, int NKT, int OUT>
__device__ __forceinline__ void layer2(const _Float16* __restrict__ wb,
                                       _Float16* act0, _Float16* act1,
                                       int lane, int lr, int kg, f32x4 z4) {
    f32x4 acc0[NOT], acc1[NOT];
#pragma unroll
    for (int kt = 0; kt < NKT; ++kt) {
        const half8 bf0 = *(const half8*)(act0 + kt * 512 + lane * 8);
        const half8 bf1 = *(const half8*)(act1 + kt * 512 + lane * 8);
#pragma unroll
        for (int ot = 0; ot < NOT; ++ot) {
            const half8 wf =
                *(const half8*)(wb + (ot * NKT + kt) * 512 + lane * 8);
            acc0[ot] = __builtin_amdgcn_mfma_f32_16x16x32_f16(
                wf, bf0, kt == 0 ? z4 : acc0[ot], 0, 0, 0);
            acc1[ot] = __builtin_amdgcn_mfma_f32_16x16x32_f16(
                wf, bf1, kt == 0 ? z4 : acc1[ot], 0, 0, 0);
        }
    }
    epilogue<NOT, OUT>(acc0, act0, lr, kg);
    epilogue<NOT, OUT>(acc1, act1, lr, kg);
}

__device__ __forceinline__ half8 load_xb(const float* __restrict__ x,
                                         int row0, int lr, int kg) {
    half8 xb = {};
    if (kg < 2) {
        const float* xr = x + (size_t)(row0 + lr) * 11 + kg * 8;
#pragma unroll
        for (int e = 0; e < 8; ++e) {
            const int k = kg * 8 + e;
            float v = (k < 11) ? xr[e] : ((k == 11) ? 1.0f : 0.0f);
            xb[e] = (_Float16)v;
        }
    }
    return xb;
}

__global__ __launch_bounds__(256, 4) void longnet_mlp_r8(
    const float* __restrict__ x,
    const float* __restrict__ W0, const float* __restrict__ b0,
    const float* __restrict__ W1, const float* __restrict__ b1,
    const float* __restrict__ W2, const float* __restrict__ b2,
    const float* __restrict__ W3, const float* __restrict__ b3,
    const float* __restrict__ W4, const float* __restrict__ b4,
    const float* __restrict__ W5, const float* __restrict__ b5,
    const float* __restrict__ W6, const float* __restrict__ b6,
    const float* __restrict__ W7, const float* __restrict__ b7,
    const float* __restrict__ W8, const float* __restrict__ b8,
    const float* __restrict__ W9, const float* __restrict__ b9,
    float* __restrict__ out, int n) {
    // 29 weight frags x 1024 B = 29696 B + 4 waves x 2 tiles x 2048 B act
    // = 46080 B -> 3 blocks/CU, 12 waves/CU, 24 tile-chains/CU.
    __shared__ __align__(16) _Float16 s_w[29 * 512];
    __shared__ __align__(16) _Float16 s_act[8 * 1024];

    const int tid = threadIdx.x;
    const int lane = tid & 63;
    const int wave = tid >> 6;
    const int lr = lane & 15;
    const int kg = lane >> 4;

    // ---- stage 29 weight frags into LDS (4 waves split round-robin) ----
    {
        const float* Wt[10] = {W0, W1, W2, W3, W4, W5, W6, W7, W8, W9};
        const float* bt[10] = {b0, b1, b2, b3, b4, b5, b6, b7, b8, b9};
        const int INs[10] = {11, 20, 20, 30, 30, 40, 40, 40, 20, 10};
        const int OUTs[10] = {20, 20, 30, 30, 40, 40, 40, 20, 10, 1};
        const int NOTs[10] = {2, 2, 2, 2, 3, 3, 3, 2, 1, 1};
        const int NKTs[10] = {1, 1, 1, 1, 1, 2, 2, 2, 1, 1};
        int f = 0;
        for (int L = 0; L < 10; ++L)
            for (int ot = 0; ot < NOTs[L]; ++ot)
                for (int kt = 0; kt < NKTs[L]; ++kt, ++f)
                    if ((f & 3) == wave) {
                        half8 h = make_frag(Wt[L], bt[L], INs[L], OUTs[L], ot,
                                            kt, lr, kg);
                        *(half8*)(s_w + f * 512 + lane * 8) = h;
                    }
    }

    _Float16* act0 = s_act + wave * 2048;
    _Float16* act1 = act0 + 1024;
    // zero both act tiles once; kt1 features 48..63 stay zero forever
    // (K-pad for the IN_P=64 layers, never written).
    {
        int* a32 = (int*)act0;
#pragma unroll
        for (int i = 0; i < 16; ++i) a32[i * 64 + lane] = 0;
    }
    __syncthreads();

    const f32x4 z4 = (f32x4){0.f, 0.f, 0.f, 0.f};
    const int npair = n >> 5;  // n = 2e6 -> 62500 pair-tiles (32 rows each)
    const int step = (int)gridDim.x * 4;

    for (int t = blockIdx.x * 4 + wave; t < npair; t += step) {
        const int row0 = t * 32;

        const half8 xb0 = load_xb(x, row0, lr, kg);
        const half8 xb1 = load_xb(x, row0 + 16, lr, kg);

        // layer 0 from registers (x), rest act<->act in LDS.
        {
            f32x4 acc0[2], acc1[2];
#pragma unroll
            for (int ot = 0; ot < 2; ++ot) {
                const half8 wf = *(const half8*)(s_w + ot * 512 + lane * 8);
                acc0[ot] = __builtin_amdgcn_mfma_f32_16x16x32_f16(wf, xb0, z4,
                                                                  0, 0, 0);
                acc1[ot] = __builtin_amdgcn_mfma_f32_16x16x32_f16(wf, xb1, z4,
                                                                  0, 0, 0);
            }
            epilogue<2, 20>(acc0, act0, lr, kg);
            epilogue<2, 20>(acc1, act1, lr, kg);
        }
        layer2<2, 1, 20>(s_w + 2 * 512, act0, act1, lane, lr, kg, z4);
        layer2<2, 1, 30>(s_w + 4 * 512, act0, act1, lane, lr, kg, z4);
        layer2<2, 1, 30>(s_w + 6 * 512, act0, act1, lane, lr, kg, z4);
        layer2<3, 1, 40>(s_w + 8 * 512, act0, act1, lane, lr, kg, z4);
        layer2<3, 2, 40>(s_w + 11 * 512, act0, act1, lane, lr, kg, z4);
        layer2<3, 2, 40>(s_w + 17 * 512, act0, act1, lane, lr, kg, z4);
        layer2<2, 2, 20>(s_w + 23 * 512, act0, act1, lane, lr, kg, z4);
        // L8 (20->10): writes features 0..15 only; stale 16..31 are killed
        // by w9's zero columns (k>10 of w9 frag is zero).
        layer2<1, 1, 10>(s_w + 27 * 512, act0, act1, lane, lr, kg, z4);

        // final layer 10->1 (+ReLU): feature 0 lives in kg==0, reg 0.
        {
            const half8 wf = *(const half8*)(s_w + 28 * 512 + lane * 8);
            const half8 bf0 = *(const half8*)(act0 + lane * 8);
            const half8 bf1 = *(const half8*)(act1 + lane * 8);
            f32x4 aF0 =
                __builtin_amdgcn_mfma_f32_16x16x32_f16(wf, bf0, z4, 0, 0, 0);
            f32x4 aF1 =
                __builtin_amdgcn_mfma_f32_16x16x32_f16(wf, bf1, z4, 0, 0, 0);
            if (kg == 0) {
                out[row0 + lr] = fmaxf(aF0[0], 0.0f);
                out[row0 + 16 + lr] = fmaxf(aF1[0], 0.0f);
            }
        }
    }
}

extern "C" void kernel_launch(void* const* d_in, const int* in_sizes, int n_in,
                              void* d_out, int out_size, void* d_ws, size_t ws_size,
                              hipStream_t stream) {
    const float* x = (const float*)d_in[0];
    const float* W0 = (const float*)d_in[1];
    const float* b0 = (const float*)d_in[2];
    const float* W1 = (const float*)d_in[3];
    const float* b1 = (const float*)d_in[4];
    const float* W2 = (const float*)d_in[5];
    const float* b2 = (const float*)d_in[6];
    const float* W3 = (const float*)d_in[7];
    const float* b3 = (const float*)d_in[8];
    const float* W4 = (const float*)d_in[9];
    const float* b4 = (const float*)d_in[10];
    const float* W5 = (const float*)d_in[11];
    const float* b5 = (const float*)d_in[12];
    const float* W6 = (const float*)d_in[13];
    const float* b6 = (const float*)d_in[14];
    const float* W7 = (const float*)d_in[15];
    const float* b7 = (const float*)d_in[16];
    const float* W8 = (const float*)d_in[17];
    const float* b8 = (const float*)d_in[18];
    const float* W9 = (const float*)d_in[19];
    const float* b9 = (const float*)d_in[20];
    float* out = (float*)d_out;

    const int n = in_sizes[0] / 11;  // 2,000,000 rows
    const int grid = 768;            // 3 blocks/CU resident, persistent

    longnet_mlp_r8<<<grid, 256, 0, stream>>>(
        x, W0, b0, W1, b1, W2, b2, W3, b3, W4, b4, W5, b5, W6, b6, W7, b7, W8,
        b8, W9, b9, out, n);
}

// Round 9
// 179.609 us; speedup vs baseline: 1.1592x; 1.1592x over previous
//
#include <hip/hip_runtime.h>
#include <math.h>

// 10-layer MLP, fp16 MFMA (fp32 acc), two 16-sample tiles in flight/wave.
// R9: K=16 MFMA (16x16x16f16) for K-remainders: IN=40 layers = kt0(K32,x32)
// + kt1(K16,x16); L0/L9 are single x16 MFMAs. Weight LDS 24064 B, act
// 2x1536 B/wave -> total 36352 B -> 4 blocks/CU WITH 2-tile ILP.
// kt1 act region stored in x16 B-frag layout == D-layout of acc[ot=2]
// (identity) -> epilogue kt1 write = linear b64 at lane*8, conflict-free.
// kt0 act region XOR-swizzled (bit7->4, bit8->5, 16B granule): epilogue
// writes 4-way -> 2-way (free); b128 reads stay conflict-free (bijective
// 16B-slot permutation). All LDS addresses precomputed outside the loop.
// Bias folded as augmented-K column (marker 1.0 at feature==next-IN).

typedef _Float16 half8 __attribute__((ext_vector_type(8)));
typedef _Float16 half4 __attribute__((ext_vector_type(4)));
typedef _Float16 half2 __attribute__((ext_vector_type(2)));
typedef float f32x4 __attribute__((ext_vector_type(4)));

__device__ __forceinline__ int swz(int a) {  // kt0 byte-offset swizzle
    return a ^ (((a >> 7) & 1) << 4) ^ (((a >> 8) & 1) << 5);
}

__device__ __forceinline__ float swish_f(float a) {
    float e = __expf(-a);
    return a * __builtin_amdgcn_rcpf(1.0f + e);
}

__device__ __forceinline__ half4 pack4(const float (&v)[4]) {
    auto lo = __builtin_amdgcn_cvt_pkrtz(v[0], v[1]);
    auto hi = __builtin_amdgcn_cvt_pkrtz(v[2], v[3]);
    union {
        half4 h4;
        half2 h2[2];
    } u;
    u.h2[0] = __builtin_bit_cast(half2, lo);
    u.h2[1] = __builtin_bit_cast(half2, hi);
    return u.h4;
}

// x32 weight frag (K=32, k=kg*8+e): row=ot*16+lr; k==IN -> bias.
__device__ __forceinline__ half8 make_frag32(const float* __restrict__ W,
                                             const float* __restrict__ b,
                                             int IN, int OUT, int ot, int lr,
                                             int kg) {
    const int r = ot * 16 + lr;
    half8 h;
#pragma unroll
    for (int e = 0; e < 8; ++e) {
        const int k = kg * 8 + e;
        float v = 0.0f;
        if (r < OUT) {
            if (k < IN)
                v = W[r * IN + k];
            else if (k == IN)
                v = b[r];
        }
        h[e] = (_Float16)v;
    }
    return h;
}

// x16 weight frag (K=16, k=kb+kg*4+e): row=ot*16+lr; k==IN -> bias.
__device__ __forceinline__ half4 make_frag16(const float* __restrict__ W,
                                             const float* __restrict__ b,
                                             int IN, int OUT, int ot, int kb,
                                             int lr, int kg) {
    const int r = ot * 16 + lr;
    half4 h;
#pragma unroll
    for (int e = 0; e < 4; ++e) {
        const int k = kb + kg * 4 + e;
        float v = 0.0f;
        if (r < OUT) {
            if (k < IN)
                v = W[r * IN + k];
            else if (k == IN)
                v = b[r];
        }
        h[e] = (_Float16)v;
    }
    return h;
}

struct TP {                 // per-tile precomputed LDS pointers
    const half8* r0;        // kt0 b128 read (swizzled)
    const half4* r1;        // kt1 b64 read (linear)
    _Float16* w0;           // kt0 write, ot=0 (swizzled)
    _Float16* w1;           // kt0 write, ot=1 (swizzled)
    _Float16* wk;           // kt1 write (linear, == r1 address)
};

// kt0 epilogue (R6-validated D->B mapping, swizzle pre-applied in w0/w1).
template <int NK0, int MARK, int NOT>
__device__ __forceinline__ void epi_kt0(const f32x4 (&A)[NOT], const TP& t,
                                        int kg) {
#pragma unroll
    for (int ot = 0; ot < NK0; ++ot) {
        float v[4];
#pragma unroll
        for (int r = 0; r < 4; ++r) {
            v[r] = swish_f(A[ot][r]);
            if (ot == MARK / 16 && ot * 16 + kg * 4 + r == MARK) v[r] = 1.0f;
        }
        _Float16* wp = (ot == 0) ? t.w0 : t.w1;
        *(half4*)wp = pack4(v);
    }
}

// kt1 epilogue: D-layout of acc IS the x16 B-frag layout -> identity b64.
template <int MREL>
__device__ __forceinline__ void epi_kt1(const f32x4& a, const TP& t, int kg) {
    float v[4];
#pragma unroll
    for (int r = 0; r < 4; ++r) {
        v[r] = swish_f(a[r]);
        if constexpr (MREL >= 0) {
            if (kg * 4 + r == MREL) v[r] = 1.0f;
        }
    }
    *(half4*)t.wk = pack4(v);
}

template <int NOT, bool K1>
__device__ __forceinline__ void compute2(const _Float16* __restrict__ w32,
                                         const _Float16* __restrict__ w16,
                                         const TP& t0, const TP& t1,
                                         f32x4 (&A)[NOT], f32x4 (&B)[NOT],
                                         int lane) {
    const f32x4 z4 = {0.f, 0.f, 0.f, 0.f};
    const half8 b0 = *t0.r0;
    const half8 b1 = *t1.r0;
#pragma unroll
    for (int ot = 0; ot < NOT; ++ot) {
        const half8 wf = *(const half8*)(w32 + ot * 512 + lane * 8);
        A[ot] = __builtin_amdgcn_mfma_f32_16x16x32_f16(wf, b0, z4, 0, 0, 0);
        B[ot] = __builtin_amdgcn_mfma_f32_16x16x32_f16(wf, b1, z4, 0, 0, 0);
    }
    if constexpr (K1) {
        const half4 c0 = *t0.r1;
        const half4 c1 = *t1.r1;
#pragma unroll
        for (int ot = 0; ot < NOT; ++ot) {
            const half4 wg = *(const half4*)(w16 + ot * 256 + lane * 4);
            A[ot] = __builtin_amdgcn_mfma_f32_16x16x16f16(wg, c0, A[ot], 0, 0, 0);
            B[ot] = __builtin_amdgcn_mfma_f32_16x16x16f16(wg, c1, B[ot], 0, 0, 0);
        }
    }
}

// One layer for both tiles. NK0 = #acc groups to kt0; NOT>NK0 -> acc[NK0]
// goes to kt1 (x16 identity). MARK: kt0 marker feature; MREL: kt1 marker
// (feature - 32, or absolute for L8); use 1000/-1 for "none".
template <int NOT, bool K1, int NK0, int MARK, int MREL>
__device__ __forceinline__ void layerX(const _Float16* __restrict__ w32,
                                       const _Float16* __restrict__ w16,
                                       const TP& t0, const TP& t1, int lane,
                                       int kg) {
    f32x4 A[NOT], B[NOT];
    compute2<NOT, K1>(w32, w16, t0, t1, A, B, lane);
    epi_kt0<NK0, MARK>(A, t0, kg);
    epi_kt0<NK0, MARK>(B, t1, kg);
    if constexpr (NOT > NK0) {
        epi_kt1<MREL>(A[NK0], t0, kg);
        epi_kt1<MREL>(B[NK0], t1, kg);
    }
}

__device__ __forceinline__ half4 load_x4(const float* __restrict__ x,
                                         int row0, int lr, int kg) {
    half4 b = {};
    const float* xr = x + (size_t)(row0 + lr) * 11;
#pragma unroll
    for (int e = 0; e < 4; ++e) {
        const int k = kg * 4 + e;
        float v = (k < 11) ? xr[k] : ((k == 11) ? 1.0f : 0.0f);
        b[e] = (_Float16)v;
    }
    return b;
}

__global__ __launch_bounds__(256, 4) void longnet_mlp_r9(
    const float* __restrict__ x,
    const float* __restrict__ W0, const float* __restrict__ b0,
    const float* __restrict__ W1, const float* __restrict__ b1,
    const float* __restrict__ W2, const float* __restrict__ b2,
    const float* __restrict__ W3, const float* __restrict__ b3,
    const float* __restrict__ W4, const float* __restrict__ b4,
    const float* __restrict__ W5, const float* __restrict__ b5,
    const float* __restrict__ W6, const float* __restrict__ b6,
    const float* __restrict__ W7, const float* __restrict__ b7,
    const float* __restrict__ W8, const float* __restrict__ b8,
    const float* __restrict__ W9, const float* __restrict__ b9,
    float* __restrict__ out, int n) {
    // weights: 18 x32 frags (9216 f16) + 11 x16 frags (2816 f16) = 24064 B
    // act: 4 waves x 2 tiles x 768 f16 = 12288 B.  total 36352 B -> 4/CU.
    __shared__ __align__(16) _Float16 s_w[12032];
    __shared__ __align__(16) _Float16 s_act[6144];

    const int tid = threadIdx.x;
    const int lane = tid & 63;
    const int wave = tid >> 6;
    const int lr = lane & 15;
    const int kg = lane >> 4;
    const int kgl = kg & 1;
    const int kgh = kg >> 1;

    _Float16* const s_w16 = s_w + 9216;

    // ---- stage 29 weight frags (4 waves round-robin) ----
    {
        const float* Wt[10] = {W0, W1, W2, W3, W4, W5, W6, W7, W8, W9};
        const float* bt[10] = {b0, b1, b2, b3, b4, b5, b6, b7, b8, b9};
        const int INs[10] = {11, 20, 20, 30, 30, 40, 40, 40, 20, 10};
        const int OUTs[10] = {20, 20, 30, 30, 40, 40, 40, 20, 10, 1};
        // x32 frags: L1..L8 kt0
        const int L32[18] = {1, 1, 2, 2, 3, 3, 4, 4, 4, 5, 5, 5, 6, 6, 6, 7, 7, 8};
        const int O32[18] = {0, 1, 0, 1, 0, 1, 0, 1, 2, 0, 1, 2, 0, 1, 2, 0, 1, 0};
#pragma unroll
        for (int i = 0; i < 18; ++i)
            if ((i & 3) == wave) {
                const int L = L32[i];
                half8 h = make_frag32(Wt[L], bt[L], INs[L], OUTs[L], O32[i],
                                      lr, kg);
                *(half8*)(s_w + i * 512 + lane * 8) = h;
            }
        // x16 frags: L0 (kb 0), L5/6/7 kt1 (kb 32), L9 (kb 0)
        const int L16[11] = {0, 0, 5, 5, 5, 6, 6, 6, 7, 7, 9};
        const int O16[11] = {0, 1, 0, 1, 2, 0, 1, 2, 0, 1, 0};
        const int KB16[11] = {0, 0, 32, 32, 32, 32, 32, 32, 32, 32, 0};
#pragma unroll
        for (int i = 0; i < 11; ++i)
            if (((18 + i) & 3) == wave) {
                const int L = L16[i];
                half4 h = make_frag16(Wt[L], bt[L], INs[L], OUTs[L], O16[i],
                                      KB16[i], lr, kg);
                *(half4*)(s_w16 + i * 256 + lane * 4) = h;
            }
    }

    // ---- per-tile pointer setup (all LDS addresses precomputed) ----
    char* const c0 = (char*)s_act + wave * 3072;
    char* const c1 = c0 + 1536;
    const int rd0 = swz(lane * 16);
    const int rk1 = 1024 + lane * 8;
    const int wo0 = swz((kgh & 3) * 256 + lr * 16 + kgl * 8);
    const int wo1 = swz(((2 + kgh) & 3) * 256 + lr * 16 + kgl * 8);
    const TP t0 = {(const half8*)(c0 + rd0), (const half4*)(c0 + rk1),
                   (_Float16*)(c0 + wo0), (_Float16*)(c0 + wo1),
                   (_Float16*)(c0 + rk1)};
    const TP t1 = {(const half8*)(c1 + rd0), (const half4*)(c1 + rk1),
                   (_Float16*)(c1 + wo0), (_Float16*)(c1 + wo1),
                   (_Float16*)(c1 + rk1)};

    // zero both act tiles once (3072 B = 768 dwords).
    {
        int* a32 = (int*)c0;
#pragma unroll
        for (int i = 0; i < 12; ++i) a32[i * 64 + lane] = 0;
    }
    __syncthreads();

    const f32x4 z4 = {0.f, 0.f, 0.f, 0.f};
    const int npair = n >> 5;  // 62500 pair-tiles of 32 rows
    const int step = (int)gridDim.x * 4;

    for (int t = blockIdx.x * 4 + wave; t < npair; t += step) {
        const int row0 = t * 32;

        // L0 (11->20): single x16 MFMA, B straight from global x.
        {
            const half4 xb0 = load_x4(x, row0, lr, kg);
            const half4 xb1 = load_x4(x, row0 + 16, lr, kg);
            f32x4 A[2], B[2];
#pragma unroll
            for (int ot = 0; ot < 2; ++ot) {
                const half4 wg = *(const half4*)(s_w16 + ot * 256 + lane * 4);
                A[ot] = __builtin_amdgcn_mfma_f32_16x16x16f16(wg, xb0, z4, 0, 0, 0);
                B[ot] = __builtin_amdgcn_mfma_f32_16x16x16f16(wg, xb1, z4, 0, 0, 0);
            }
            epi_kt0<2, 20>(A, t0, kg);
            epi_kt0<2, 20>(B, t1, kg);
        }
        layerX<2, false, 2, 20, -1>(s_w + 0 * 512, s_w, t0, t1, lane, kg);   // L1
        layerX<2, false, 2, 30, -1>(s_w + 2 * 512, s_w, t0, t1, lane, kg);   // L2
        layerX<2, false, 2, 30, -1>(s_w + 4 * 512, s_w, t0, t1, lane, kg);   // L3
        layerX<3, false, 2, 1000, 8>(s_w + 6 * 512, s_w, t0, t1, lane, kg);  // L4
        layerX<3, true, 2, 1000, 8>(s_w + 9 * 512, s_w16 + 2 * 256, t0, t1, lane, kg);   // L5
        layerX<3, true, 2, 1000, 8>(s_w + 12 * 512, s_w16 + 5 * 256, t0, t1, lane, kg);  // L6
        layerX<2, true, 2, 20, -1>(s_w + 15 * 512, s_w16 + 8 * 256, t0, t1, lane, kg);   // L7
        layerX<1, false, 0, 1000, 10>(s_w + 17 * 512, s_w, t0, t1, lane, kg);            // L8 -> kt1

        // L9 (10->1) + ReLU: single x16 on kt1; feature 0 at kg==0, r==0.
        {
            const half4 wg = *(const half4*)(s_w16 + 10 * 256 + lane * 4);
            f32x4 F0 = __builtin_amdgcn_mfma_f32_16x16x16f16(wg, *t0.r1, z4, 0, 0, 0);
            f32x4 F1 = __builtin_amdgcn_mfma_f32_16x16x16f16(wg, *t1.r1, z4, 0, 0, 0);
            if (kg == 0) {
                out[row0 + lr] = fmaxf(F0[0], 0.0f);
                out[row0 + 16 + lr] = fmaxf(F1[0], 0.0f);
            }
        }
    }
}

extern "C" void kernel_launch(void* const* d_in, const int* in_sizes, int n_in,
                              void* d_out, int out_size, void* d_ws, size_t ws_size,
                              hipStream_t stream) {
    const float* x = (const float*)d_in[0];
    const float* W0 = (const float*)d_in[1];
    const float* b0 = (const float*)d_in[2];
    const float* W1 = (const float*)d_in[3];
    const float* b1 = (const float*)d_in[4];
    const float* W2 = (const float*)d_in[5];
    const float* b2 = (const float*)d_in[6];
    const float* W3 = (const float*)d_in[7];
    const float* b3 = (const float*)d_in[8];
    const float* W4 = (const float*)d_in[9];
    const float* b4 = (const float*)d_in[10];
    const float* W5 = (const float*)d_in[11];
    const float* b5 = (const float*)d_in[12];
    const float* W6 = (const float*)d_in[13];
    const float* b6 = (const float*)d_in[14];
    const float* W7 = (const float*)d_in[15];
    const float* b7 = (const float*)d_in[16];
    const float* W8 = (const float*)d_in[17];
    const float* b8 = (const float*)d_in[18];
    const float* W9 = (const float*)d_in[19];
    const float* b9 = (const float*)d_in[20];
    float* out = (float*)d_out;

    const int n = in_sizes[0] / 11;  // 2,000,000 rows
    const int grid = 1024;           // 4 blocks/CU resident, persistent

    longnet_mlp_r9<<<grid, 256, 0, stream>>>(
        x, W0, b0, W1, b1, W2, b2, W3, b3, W4, b4, W5, b5, W6, b6, W7, b7, W8,
        b8, W9, b9, out, n);
}